// Round 12
// baseline (471.244 us; speedup 1.0000x reference)
//
#include <hip/hip_runtime.h>

#define BB 16
#define CC 128
#define HH 112
#define NHH 4
#define WSZ 7
#define NN 49
#define SH 3

typedef _Float16 h8 __attribute__((ext_vector_type(8)));
typedef _Float16 h4 __attribute__((ext_vector_type(4)));
typedef float f4 __attribute__((ext_vector_type(4)));

__device__ __forceinline__ int rid3(int p) { return p < 105 ? 0 : (p < 109 ? 1 : 2); }

// XOR-swizzled element offset inside a row-major [rows][CH*8] fp16 tile.
#define SWZ(row, j, CH) ((row) * ((CH) * 8) + (((((j) >> 3) ^ (row)) & ((CH) - 1)) << 3) + ((j) & 7))

__device__ __forceinline__ h4 pack4(f4 v) {
  h4 r; r[0] = (_Float16)v[0]; r[1] = (_Float16)v[1];
  r[2] = (_Float16)v[2]; r[3] = (_Float16)v[3];
  return r;
}

// ---------------- patch embed: 4x4 stride-4 conv -> t0 (fp16, [B,H,W,C]) ----
__global__ __launch_bounds__(256) void conv_embed(const float* __restrict__ x,
    const float* __restrict__ cw, const float* __restrict__ cb, _Float16* __restrict__ t0) {
  __shared__ float xs[3][4][448];
  __shared__ float wT[48][128];
  __shared__ float cbs[128];
  int bid = blockIdx.x;
  int b = bid / HH, oh = bid % HH;
  int tid = threadIdx.x;
  for (int idx = tid; idx < 3 * 4 * 448; idx += 256) {
    int ch = idx / 1792;
    int r = (idx / 448) & 3;
    int col = idx % 448;
    xs[ch][r][col] = x[((b * 3 + ch) * 448 + (oh * 4 + r)) * 448 + col];
  }
  for (int idx = tid; idx < 6144; idx += 256) {
    int c = idx / 48, k = idx - c * 48;
    wT[k][c] = cw[idx];
  }
  if (tid < 128) cbs[tid] = cb[tid];
  __syncthreads();
  int c0 = (tid & 31) << 2;
  int gg = tid >> 5;
  for (int it = 0; it < 4; ++it) {
    int gw0 = it * 32 + gg * 4;
    if (gw0 >= HH) break;
    float acc[4][4] = {};
#pragma unroll
    for (int k = 0; k < 48; ++k) {
      int ch = k >> 4, r = (k >> 2) & 3, j = k & 3;
      float4 wv = *(const float4*)&wT[k][c0];
#pragma unroll
      for (int d = 0; d < 4; ++d) {
        float xv = xs[ch][r][(gw0 + d) * 4 + j];
        acc[d][0] = fmaf(xv, wv.x, acc[d][0]);
        acc[d][1] = fmaf(xv, wv.y, acc[d][1]);
        acc[d][2] = fmaf(xv, wv.z, acc[d][2]);
        acc[d][3] = fmaf(xv, wv.w, acc[d][3]);
      }
    }
    float4 bv = *(const float4*)&cbs[c0];
#pragma unroll
    for (int d = 0; d < 4; ++d) {
      int gw = gw0 + d;
      h4 o;
      o[0] = (_Float16)(acc[d][0] + bv.x); o[1] = (_Float16)(acc[d][1] + bv.y);
      o[2] = (_Float16)(acc[d][2] + bv.z); o[3] = (_Float16)(acc[d][3] + bv.w);
      *(h4*)&t0[((size_t)(b * HH + oh) * HH + gw) * CC + c0] = o;
    }
  }
}

// ---------------- prep: fp16 weights (Q-scale folded), scaled qb, fp16 bias table ----
__global__ void prep(const float* __restrict__ qw, const float* __restrict__ qb,
                     const float* __restrict__ pw, const float* __restrict__ rpb,
                     _Float16* __restrict__ qwh, float* __restrict__ qbs,
                     _Float16* __restrict__ pwh, _Float16* __restrict__ biasT) {
  const float scale = 0.17677669529663687f;  // 1/sqrt(32)
  int tid0 = blockIdx.x * blockDim.x + threadIdx.x;
  int stride = gridDim.x * blockDim.x;
  for (int idx = tid0; idx < 2 * 384 * 128; idx += stride) {
    int n = (idx >> 7) % 384;
    float v = qw[idx];
    if (n < 128) v *= scale;
    qwh[idx] = (_Float16)v;
  }
  for (int idx = tid0; idx < 2 * 384; idx += stride) {
    int n = idx % 384;
    float v = qb[idx];
    if (n < 128) v *= scale;
    qbs[idx] = v;
  }
  for (int idx = tid0; idx < 2 * 128 * 128; idx += stride)
    pwh[idx] = (_Float16)pw[idx];
  for (int idx = tid0; idx < 2 * 4 * 4 * 4 * 64 * 4; idx += stride) {
    int r = idx & 3;
    int lane = (idx >> 2) & 63;
    int it = (idx >> 8) & 3;
    int jt = (idx >> 10) & 3;
    int hh = (idx >> 12) & 3;
    int ll = idx >> 14;
    int i = it * 16 + (lane & 15);
    int j = jt * 16 + ((lane >> 4) * 4) + r;
    float v = 0.f;
    if (i < NN && j < NN) {
      int rel = ((i / 7 - j / 7) + 6) * 13 + ((i % 7 - j % 7) + 6);
      v = rpb[(ll * 169 + rel) * NHH + hh];
    }
    biasT[idx] = (_Float16)v;
  }
}

// ---------------- fused window layer: 32 KB LDS, 5 blocks/CU (exact 160 KB fit) ----
// grid = 4096 (1 block = 1 window), 4 waves; wave = head everywhere.
// LDS: region A @0    : win[64][128] CH=16 (read by K/Q/V passes) -> Y overlay (layer0, post-B1')
//      region B @8192 : 2048/head, own-wave time-shared K->Q->VT->P->O[64tok][32d]
#define RA 0
#define RB 8192
__global__ __launch_bounds__(256, 5) void swin_layer(
    const _Float16* __restrict__ tin, _Float16* __restrict__ toutB, float* __restrict__ outN,
    const _Float16* __restrict__ qwh, const float* __restrict__ qbs,
    const _Float16* __restrict__ pwh, const float* __restrict__ pb,
    const _Float16* __restrict__ biasT, int shift, int writeN) {
  __shared__ _Float16 sm[16384];  // 32768 B x 5 blocks = 163840 B = full LDS pool

  int tid = threadIdx.x;
  // bijective XCD swizzle (4096 % 8 == 0): each XCD gets a contiguous wid chunk
  int wid = (blockIdx.x & 7) * 512 + (blockIdx.x >> 3);
  int b = wid >> 8;
  int wh = (wid >> 4) & 15, ww = wid & 15;
  int w = tid >> 6, l = tid & 63, li = l & 15, lg = l >> 4;
  int h = w;
  const int hb = RB + h * 2048;

  // ---- phase 1: stage window tokens (rows 49..63 = finite garbage, masked later) ----
  for (int c = tid; c < 64 * 16; c += 256) {
    int n = c >> 4, k0 = (c & 15) * 8;
    int gh = wh * WSZ + n / 7 + shift; if (gh >= HH) gh -= HH;
    int gw = ww * WSZ + n % 7 + shift; if (gw >= HH) gw -= HH;
    h8 v = *(const h8*)(tin + ((size_t)(b * HH + gh) * HH + gw) * CC + k0);
    *(h8*)&sm[RA + SWZ(n, k0, 16)] = v;
  }
  __syncthreads();  // B0

  h8 Kf[4], Qf[4];

  // ---- merged K+Q pass: two independent acc chains share the bW LDS reads ----
  {
    f4 accK[2][4], accQ[2][4];
#pragma unroll
    for (int half = 0; half < 2; ++half) {
      float4 bk = *(const float4*)&qbs[128 + h * 32 + half * 16 + lg * 4];
      float4 bq = *(const float4*)&qbs[h * 32 + half * 16 + lg * 4];
#pragma unroll
      for (int nt = 0; nt < 4; ++nt) {
        accK[half][nt] = f4{bk.x, bk.y, bk.z, bk.w};
        accQ[half][nt] = f4{bq.x, bq.y, bq.z, bq.w};
      }
    }
#pragma unroll
    for (int ks = 0; ks < 4; ++ks) {
      h8 bW[4];
#pragma unroll
      for (int nt = 0; nt < 4; ++nt)
        bW[nt] = *(const h8*)&sm[RA + SWZ(nt * 16 + li, ks * 32 + lg * 8, 16)];
#pragma unroll
      for (int half = 0; half < 2; ++half) {
        h8 aK = *(const h8*)(qwh + (size_t)((8 + 2 * h + half) * 16 + li) * 128 + ks * 32 + lg * 8);
        h8 aQ = *(const h8*)(qwh + (size_t)((2 * h + half) * 16 + li) * 128 + ks * 32 + lg * 8);
#pragma unroll
        for (int nt = 0; nt < 4; ++nt) {
          accK[half][nt] = __builtin_amdgcn_mfma_f32_16x16x32_f16(aK, bW[nt], accK[half][nt], 0, 0, 0);
          accQ[half][nt] = __builtin_amdgcn_mfma_f32_16x16x32_f16(aQ, bW[nt], accQ[half][nt], 0, 0, 0);
        }
      }
    }
    // K round-trip through region B -> Kf
#pragma unroll
    for (int half = 0; half < 2; ++half)
#pragma unroll
      for (int nt = 0; nt < 4; ++nt)
        *(h4*)&sm[hb + SWZ(nt * 16 + li, half * 16 + lg * 4, 4)] = pack4(accK[half][nt]);
#pragma unroll
    for (int jt = 0; jt < 4; ++jt)
      Kf[jt] = *(const h8*)&sm[hb + SWZ(jt * 16 + li, lg * 8, 4)];
    // Q round-trip (same-wave DS ordering: writes cannot pass the Kf reads)
#pragma unroll
    for (int half = 0; half < 2; ++half)
#pragma unroll
      for (int nt = 0; nt < 4; ++nt)
        *(h4*)&sm[hb + SWZ(nt * 16 + li, half * 16 + lg * 4, 4)] = pack4(accQ[half][nt]);
#pragma unroll
    for (int it = 0; it < 4; ++it)
      Qf[it] = *(const h8*)&sm[hb + SWZ(it * 16 + li, lg * 8, 4)];
  }

  // ---- V pass (swapped operands): C(row=tok,col=d) -> VT[d][tok] h4 writes ----
  {
    f4 acc[4][2];
#pragma unroll
    for (int ct = 0; ct < 2; ++ct) {
      float bv = qbs[256 + h * 32 + ct * 16 + li];
#pragma unroll
      for (int nt = 0; nt < 4; ++nt) acc[nt][ct] = f4{bv, bv, bv, bv};
    }
#pragma unroll
    for (int ks = 0; ks < 4; ++ks) {
      h8 bW[4];
#pragma unroll
      for (int nt = 0; nt < 4; ++nt)
        bW[nt] = *(const h8*)&sm[RA + SWZ(nt * 16 + li, ks * 32 + lg * 8, 16)];
      h8 wv[2];
#pragma unroll
      for (int ct = 0; ct < 2; ++ct)
        wv[ct] = *(const h8*)(qwh + (size_t)((16 + 2 * h + ct) * 16 + li) * 128 + ks * 32 + lg * 8);
#pragma unroll
      for (int nt = 0; nt < 4; ++nt)
#pragma unroll
        for (int ct = 0; ct < 2; ++ct)
          acc[nt][ct] = __builtin_amdgcn_mfma_f32_16x16x32_f16(bW[nt], wv[ct], acc[nt][ct], 0, 0, 0);
    }
#pragma unroll
    for (int nt = 0; nt < 4; ++nt)
#pragma unroll
      for (int ct = 0; ct < 2; ++ct)
        *(h4*)&sm[hb + SWZ(ct * 16 + li, nt * 16 + lg * 4, 8)] = pack4(acc[nt][ct]);
  }

  // ---- S^T = K . Q^T + bias + mask, softmax in regs ----
  float inv[4];
  h4 P4[4][4];
  {
    f4 s[4][4];
    const _Float16* bT = biasT + h * 4096;
#pragma unroll
    for (int jt = 0; jt < 4; ++jt)
#pragma unroll
      for (int it = 0; it < 4; ++it) {
        h4 bb = *(const h4*)&bT[(jt * 4 + it) * 256 + l * 4];
        s[jt][it] = f4{(float)bb[0], (float)bb[1], (float)bb[2], (float)bb[3]};
      }
    __builtin_amdgcn_s_setprio(1);
#pragma unroll
    for (int jt = 0; jt < 4; ++jt)
#pragma unroll
      for (int it = 0; it < 4; ++it)
        s[jt][it] = __builtin_amdgcn_mfma_f32_16x16x32_f16(Kf[jt], Qf[it], s[jt][it], 0, 0, 0);
    __builtin_amdgcn_s_setprio(0);
#pragma unroll
    for (int jt = 0; jt < 4; ++jt)
#pragma unroll
      for (int it = 0; it < 4; ++it)
#pragma unroll
        for (int r = 0; r < 4; ++r) {
          int j = jt * 16 + lg * 4 + r;
          s[jt][it][r] = (j < NN) ? s[jt][it][r] : -1e30f;
        }
    if (shift && (wh == 15 || ww == 15)) {
      int regi[4], regj[4][4];
#pragma unroll
      for (int it = 0; it < 4; ++it) {
        int i = it * 16 + li;
        regi[it] = rid3(wh * WSZ + i / 7) * 3 + rid3(ww * WSZ + i % 7);
      }
#pragma unroll
      for (int jt = 0; jt < 4; ++jt)
#pragma unroll
        for (int r = 0; r < 4; ++r) {
          int j = jt * 16 + lg * 4 + r;
          regj[jt][r] = rid3(wh * WSZ + j / 7) * 3 + rid3(ww * WSZ + j % 7);
        }
#pragma unroll
      for (int jt = 0; jt < 4; ++jt)
#pragma unroll
        for (int it = 0; it < 4; ++it)
#pragma unroll
          for (int r = 0; r < 4; ++r)
            if (regj[jt][r] != regi[it]) s[jt][it][r] -= 100.f;
    }
#pragma unroll
    for (int it = 0; it < 4; ++it) {
      float mx = -1e30f;
#pragma unroll
      for (int jt = 0; jt < 4; ++jt)
#pragma unroll
        for (int r = 0; r < 4; ++r) mx = fmaxf(mx, s[jt][it][r]);
      mx = fmaxf(mx, __shfl_xor(mx, 16));
      mx = fmaxf(mx, __shfl_xor(mx, 32));
      float sum = 0.f;
#pragma unroll
      for (int jt = 0; jt < 4; ++jt)
#pragma unroll
        for (int r = 0; r < 4; ++r) {
          float e = __expf(s[jt][it][r] - mx);
          s[jt][it][r] = e;
          sum += e;
        }
      sum += __shfl_xor(sum, 16);
      sum += __shfl_xor(sum, 32);
      inv[it] = 1.f / sum;
    }
#pragma unroll
    for (int jt = 0; jt < 4; ++jt)
#pragma unroll
      for (int it = 0; it < 4; ++it)
        P4[jt][it] = pack4(s[jt][it]);
  }

  // ---- PV: load aV (VT dead after), then P halves round-trip region B ----
  f4 o[2][4] = {};
  {
    h8 aV[2][2];
#pragma unroll
    for (int mt = 0; mt < 2; ++mt)
#pragma unroll
      for (int ks = 0; ks < 2; ++ks)
        aV[mt][ks] = *(const h8*)&sm[hb + SWZ(mt * 16 + li, ks * 32 + lg * 8, 8)];
#pragma unroll
    for (int half = 0; half < 2; ++half) {
#pragma unroll
      for (int jt2 = 0; jt2 < 2; ++jt2)
#pragma unroll
        for (int it = 0; it < 4; ++it)
          *(h4*)&sm[hb + SWZ(it * 16 + li, jt2 * 16 + lg * 4, 4)] = P4[half * 2 + jt2][it];
      h8 bP[4];
#pragma unroll
      for (int nt = 0; nt < 4; ++nt)
        bP[nt] = *(const h8*)&sm[hb + SWZ(nt * 16 + li, lg * 8, 4)];
      __builtin_amdgcn_s_setprio(1);
#pragma unroll
      for (int mt = 0; mt < 2; ++mt)
#pragma unroll
        for (int nt = 0; nt < 4; ++nt)
          o[mt][nt] = __builtin_amdgcn_mfma_f32_16x16x32_f16(aV[mt][half], bP[nt], o[mt][nt], 0, 0, 0);
      __builtin_amdgcn_s_setprio(0);
    }
  }

  // ---- prefetch proj weights + bias (latency hides under O-write + B1') ----
  h8 pa[2][4];
  float4 pbb[2];
#pragma unroll
  for (int mi = 0; mi < 2; ++mi) {
    pbb[mi] = *(const float4*)&pb[(w * 2 + mi) * 16 + lg * 4];
#pragma unroll
    for (int ks = 0; ks < 4; ++ks)
      pa[mi][ks] = *(const h8*)(pwh + (size_t)((w * 2 + mi) * 16 + li) * 128 + ks * 32 + lg * 8);
  }

  // ---- O -> own per-head slot [64tok][32d] (P dead; no cross-wave hazard) ----
#pragma unroll
  for (int mt = 0; mt < 2; ++mt)
#pragma unroll
    for (int nt = 0; nt < 4; ++nt) {
      int i = nt * 16 + li;
      float is = inv[nt];
      h4 v = {(_Float16)(o[mt][nt][0] * is), (_Float16)(o[mt][nt][1] * is),
              (_Float16)(o[mt][nt][2] * is), (_Float16)(o[mt][nt][3] * is)};
      *(h4*)&sm[hb + SWZ(i, mt * 16 + lg * 4, 4)] = v;
    }
  __syncthreads();  // B1': all heads' O visible (also orders win reads before Y overlay)

  // ---- proj: y^T = pw . O^T ; k-chunk ks = head slot ks ----
  {
    f4 acc[2][4];
#pragma unroll
    for (int mi = 0; mi < 2; ++mi)
#pragma unroll
      for (int nt = 0; nt < 4; ++nt)
        acc[mi][nt] = f4{pbb[mi].x, pbb[mi].y, pbb[mi].z, pbb[mi].w};
    __builtin_amdgcn_s_setprio(1);
#pragma unroll
    for (int ks = 0; ks < 4; ++ks) {
      h8 bO[4];
#pragma unroll
      for (int nt = 0; nt < 4; ++nt)
        bO[nt] = *(const h8*)&sm[RB + ks * 2048 + SWZ(nt * 16 + li, lg * 8, 4)];
#pragma unroll
      for (int mi = 0; mi < 2; ++mi)
#pragma unroll
        for (int nt = 0; nt < 4; ++nt)
          acc[mi][nt] = __builtin_amdgcn_mfma_f32_16x16x32_f16(pa[mi][ks], bO[nt], acc[mi][nt], 0, 0, 0);
    }
    __builtin_amdgcn_s_setprio(0);
    if (!writeN) {
      // layer 0: bounce y through region A (win dead post-B1'), coalesced h8 stores
#pragma unroll
      for (int mi = 0; mi < 2; ++mi) {
        int dbase = (w * 2 + mi) * 16 + lg * 4;
#pragma unroll
        for (int nt = 0; nt < 4; ++nt) {
          int i = nt * 16 + li;
          h4 v = {(_Float16)acc[mi][nt][0], (_Float16)acc[mi][nt][1],
                  (_Float16)acc[mi][nt][2], (_Float16)acc[mi][nt][3]};
          *(h4*)&sm[RA + SWZ(i, dbase, 16)] = v;
        }
      }
      __syncthreads();  // B3
      for (int cidx = tid; cidx < NN * 16; cidx += 256) {
        int tok = cidx >> 4, c = cidx & 15;
        h8 v = *(const h8*)&sm[RA + SWZ(tok, c * 8, 16)];
        int gh = wh * WSZ + tok / 7;
        int gw = ww * WSZ + tok % 7;
        *(h8*)&toutB[((size_t)(b * HH + gh) * HH + gw) * CC + c * 8] = v;
      }
    } else {
      // layer 1: direct f32 stores with fused NCHW transpose + roll
#pragma unroll
      for (int mi = 0; mi < 2; ++mi) {
        int dbase = (w * 2 + mi) * 16 + lg * 4;
#pragma unroll
        for (int nt = 0; nt < 4; ++nt) {
          int i = nt * 16 + li;
          if (i < NN) {
            int gh = wh * WSZ + i / 7 + shift; if (gh >= HH) gh -= HH;
            int gw = ww * WSZ + i % 7 + shift; if (gw >= HH) gw -= HH;
            size_t bse = ((size_t)(b * CC + dbase) * HH + gh) * HH + gw;
            outN[bse] = acc[mi][nt][0];
            outN[bse + (size_t)HH * HH] = acc[mi][nt][1];
            outN[bse + (size_t)2 * HH * HH] = acc[mi][nt][2];
            outN[bse + (size_t)3 * HH * HH] = acc[mi][nt][3];
          }
        }
      }
    }
  }
}

extern "C" void kernel_launch(void* const* d_in, const int* in_sizes, int n_in,
                              void* d_out, int out_size, void* d_ws, size_t ws_size,
                              hipStream_t stream) {
  const float* x = (const float*)d_in[0];
  const float* cw = (const float*)d_in[1];
  const float* cb = (const float*)d_in[2];
  const float* qkvw = (const float*)d_in[3];  // (2,384,128)
  const float* qkvb = (const float*)d_in[4];  // (2,384)
  const float* projw = (const float*)d_in[5]; // (2,128,128)
  const float* projb = (const float*)d_in[6]; // (2,128)
  const float* rpb = (const float*)d_in[7];   // (2,169,4)
  float* out = (float*)d_out;

  char* ws = (char*)d_ws;
  _Float16* t0 = (_Float16*)ws;                       // 16*112*112*128 fp16
  size_t off = (size_t)BB * HH * HH * CC * 2;
  _Float16* qwh = (_Float16*)(ws + off);  off += 2 * 384 * 128 * 2;
  _Float16* pwh = (_Float16*)(ws + off);  off += 2 * 128 * 128 * 2;
  float* qbs = (float*)(ws + off);        off += 2 * 384 * 4;
  _Float16* biasT = (_Float16*)(ws + off);  // 2*16384*2

  prep<<<224, 256, 0, stream>>>(qkvw, qkvb, projw, rpb, qwh, qbs, pwh, biasT);
  conv_embed<<<BB * HH, 256, 0, stream>>>(x, cw, cb, t0);

  // layer 0: no shift, in-place on t0 (windows partition tokens)
  swin_layer<<<4096, 256, 0, stream>>>(t0, t0, nullptr,
      qwh, qbs, pwh, projb, biasT, 0, 0);
  // layer 1: shift=3, fused NCHW transpose into d_out
  swin_layer<<<4096, 256, 0, stream>>>(t0, nullptr, out,
      qwh + 384 * 128, qbs + 384, pwh + 128 * 128, projb + 128,
      biasT + 16384, SH, 1);
}

// Round 13
// 259.976 us; speedup vs baseline: 1.8126x; 1.8126x over previous
//
#include <hip/hip_runtime.h>

#define BB 16
#define CC 128
#define HH 112
#define NHH 4
#define WSZ 7
#define NN 49
#define SH 3

typedef _Float16 h8 __attribute__((ext_vector_type(8)));
typedef _Float16 h4 __attribute__((ext_vector_type(4)));
typedef float f4 __attribute__((ext_vector_type(4)));

__device__ __forceinline__ int rid3(int p) { return p < 105 ? 0 : (p < 109 ? 1 : 2); }

// XOR-swizzled element offset inside a row-major [rows][CH*8] fp16 tile.
#define SWZ(row, j, CH) ((row) * ((CH) * 8) + (((((j) >> 3) ^ (row)) & ((CH) - 1)) << 3) + ((j) & 7))

__device__ __forceinline__ h4 pack4(f4 v) {
  h4 r; r[0] = (_Float16)v[0]; r[1] = (_Float16)v[1];
  r[2] = (_Float16)v[2]; r[3] = (_Float16)v[3];
  return r;
}

// ---------------- patch embed: 4x4 stride-4 conv -> t0 (fp16, [B,H,W,C]) ----
__global__ __launch_bounds__(256) void conv_embed(const float* __restrict__ x,
    const float* __restrict__ cw, const float* __restrict__ cb, _Float16* __restrict__ t0) {
  __shared__ float xs[3][4][448];
  __shared__ float wT[48][128];
  __shared__ float cbs[128];
  int bid = blockIdx.x;
  int b = bid / HH, oh = bid % HH;
  int tid = threadIdx.x;
  for (int idx = tid; idx < 3 * 4 * 448; idx += 256) {
    int ch = idx / 1792;
    int r = (idx / 448) & 3;
    int col = idx % 448;
    xs[ch][r][col] = x[((b * 3 + ch) * 448 + (oh * 4 + r)) * 448 + col];
  }
  for (int idx = tid; idx < 6144; idx += 256) {
    int c = idx / 48, k = idx - c * 48;
    wT[k][c] = cw[idx];
  }
  if (tid < 128) cbs[tid] = cb[tid];
  __syncthreads();
  int c0 = (tid & 31) << 2;
  int gg = tid >> 5;
  for (int it = 0; it < 4; ++it) {
    int gw0 = it * 32 + gg * 4;
    if (gw0 >= HH) break;
    float acc[4][4] = {};
#pragma unroll
    for (int k = 0; k < 48; ++k) {
      int ch = k >> 4, r = (k >> 2) & 3, j = k & 3;
      float4 wv = *(const float4*)&wT[k][c0];
#pragma unroll
      for (int d = 0; d < 4; ++d) {
        float xv = xs[ch][r][(gw0 + d) * 4 + j];
        acc[d][0] = fmaf(xv, wv.x, acc[d][0]);
        acc[d][1] = fmaf(xv, wv.y, acc[d][1]);
        acc[d][2] = fmaf(xv, wv.z, acc[d][2]);
        acc[d][3] = fmaf(xv, wv.w, acc[d][3]);
      }
    }
    float4 bv = *(const float4*)&cbs[c0];
#pragma unroll
    for (int d = 0; d < 4; ++d) {
      int gw = gw0 + d;
      h4 o;
      o[0] = (_Float16)(acc[d][0] + bv.x); o[1] = (_Float16)(acc[d][1] + bv.y);
      o[2] = (_Float16)(acc[d][2] + bv.z); o[3] = (_Float16)(acc[d][3] + bv.w);
      *(h4*)&t0[((size_t)(b * HH + oh) * HH + gw) * CC + c0] = o;
    }
  }
}

// ---------------- prep: fp16 weights (Q-scale folded), scaled qb, fp16 bias table ----
__global__ void prep(const float* __restrict__ qw, const float* __restrict__ qb,
                     const float* __restrict__ pw, const float* __restrict__ rpb,
                     _Float16* __restrict__ qwh, float* __restrict__ qbs,
                     _Float16* __restrict__ pwh, _Float16* __restrict__ biasT) {
  const float scale = 0.17677669529663687f;  // 1/sqrt(32)
  int tid0 = blockIdx.x * blockDim.x + threadIdx.x;
  int stride = gridDim.x * blockDim.x;
  for (int idx = tid0; idx < 2 * 384 * 128; idx += stride) {
    int n = (idx >> 7) % 384;
    float v = qw[idx];
    if (n < 128) v *= scale;
    qwh[idx] = (_Float16)v;
  }
  for (int idx = tid0; idx < 2 * 384; idx += stride) {
    int n = idx % 384;
    float v = qb[idx];
    if (n < 128) v *= scale;
    qbs[idx] = v;
  }
  for (int idx = tid0; idx < 2 * 128 * 128; idx += stride)
    pwh[idx] = (_Float16)pw[idx];
  for (int idx = tid0; idx < 2 * 4 * 4 * 4 * 64 * 4; idx += stride) {
    int r = idx & 3;
    int lane = (idx >> 2) & 63;
    int it = (idx >> 8) & 3;
    int jt = (idx >> 10) & 3;
    int hh = (idx >> 12) & 3;
    int ll = idx >> 14;
    int i = it * 16 + (lane & 15);
    int j = jt * 16 + ((lane >> 4) * 4) + r;
    float v = 0.f;
    if (i < NN && j < NN) {
      int rel = ((i / 7 - j / 7) + 6) * 13 + ((i % 7 - j % 7) + 6);
      v = rpb[(ll * 169 + rel) * NHH + hh];
    }
    biasT[idx] = (_Float16)v;
  }
}

// ---------------- fused window layer: 32 KB LDS, O in per-head slot ----------------
// grid = 4096 (1 block = 1 window), 4 waves; wave = head everywhere.
// 4 blocks/CU is the register-file ceiling: S-phase holds s[4][4] (64 f32 acc)
// + Kf/Qf (64 operand regs) ~= the full 128/wave unified budget. (256,5) spills
// (R7, R12: FETCH/WRITE balloon, 1.8x dur); keep (256,4).
// LDS: region A @0    : win[64][128] CH=16 (read by K/Q/V passes) -> Y overlay (layer0, post-B1')
//      region B @8192 : 2048/head, own-wave time-shared K->Q->VT->P->O[64tok][32d]
#define RA 0
#define RB 8192
__global__ __launch_bounds__(256, 4) void swin_layer(
    const _Float16* __restrict__ tin, _Float16* __restrict__ toutB, float* __restrict__ outN,
    const _Float16* __restrict__ qwh, const float* __restrict__ qbs,
    const _Float16* __restrict__ pwh, const float* __restrict__ pb,
    const _Float16* __restrict__ biasT, int shift, int writeN) {
  __shared__ _Float16 sm[16384];  // 32768 B

  int tid = threadIdx.x;
  // bijective XCD swizzle (4096 % 8 == 0): each XCD gets a contiguous wid chunk
  int wid = (blockIdx.x & 7) * 512 + (blockIdx.x >> 3);
  int b = wid >> 8;
  int wh = (wid >> 4) & 15, ww = wid & 15;
  int w = tid >> 6, l = tid & 63, li = l & 15, lg = l >> 4;
  int h = w;
  const int hb = RB + h * 2048;

  // ---- phase 1: stage window tokens (rows 49..63 = finite garbage, masked later) ----
  for (int c = tid; c < 64 * 16; c += 256) {
    int n = c >> 4, k0 = (c & 15) * 8;
    int gh = wh * WSZ + n / 7 + shift; if (gh >= HH) gh -= HH;
    int gw = ww * WSZ + n % 7 + shift; if (gw >= HH) gw -= HH;
    h8 v = *(const h8*)(tin + ((size_t)(b * HH + gh) * HH + gw) * CC + k0);
    *(h8*)&sm[RA + SWZ(n, k0, 16)] = v;
  }
  __syncthreads();  // B0

  h8 Kf[4], Qf[4];

  // ---- merged K+Q pass: two independent acc chains share the bW LDS reads ----
  {
    f4 accK[2][4], accQ[2][4];
#pragma unroll
    for (int half = 0; half < 2; ++half) {
      float4 bk = *(const float4*)&qbs[128 + h * 32 + half * 16 + lg * 4];
      float4 bq = *(const float4*)&qbs[h * 32 + half * 16 + lg * 4];
#pragma unroll
      for (int nt = 0; nt < 4; ++nt) {
        accK[half][nt] = f4{bk.x, bk.y, bk.z, bk.w};
        accQ[half][nt] = f4{bq.x, bq.y, bq.z, bq.w};
      }
    }
#pragma unroll
    for (int ks = 0; ks < 4; ++ks) {
      h8 bW[4];
#pragma unroll
      for (int nt = 0; nt < 4; ++nt)
        bW[nt] = *(const h8*)&sm[RA + SWZ(nt * 16 + li, ks * 32 + lg * 8, 16)];
#pragma unroll
      for (int half = 0; half < 2; ++half) {
        h8 aK = *(const h8*)(qwh + (size_t)((8 + 2 * h + half) * 16 + li) * 128 + ks * 32 + lg * 8);
        h8 aQ = *(const h8*)(qwh + (size_t)((2 * h + half) * 16 + li) * 128 + ks * 32 + lg * 8);
#pragma unroll
        for (int nt = 0; nt < 4; ++nt) {
          accK[half][nt] = __builtin_amdgcn_mfma_f32_16x16x32_f16(aK, bW[nt], accK[half][nt], 0, 0, 0);
          accQ[half][nt] = __builtin_amdgcn_mfma_f32_16x16x32_f16(aQ, bW[nt], accQ[half][nt], 0, 0, 0);
        }
      }
    }
    // K round-trip through region B -> Kf
#pragma unroll
    for (int half = 0; half < 2; ++half)
#pragma unroll
      for (int nt = 0; nt < 4; ++nt)
        *(h4*)&sm[hb + SWZ(nt * 16 + li, half * 16 + lg * 4, 4)] = pack4(accK[half][nt]);
#pragma unroll
    for (int jt = 0; jt < 4; ++jt)
      Kf[jt] = *(const h8*)&sm[hb + SWZ(jt * 16 + li, lg * 8, 4)];
    // Q round-trip (same-wave DS ordering: writes cannot pass the Kf reads)
#pragma unroll
    for (int half = 0; half < 2; ++half)
#pragma unroll
      for (int nt = 0; nt < 4; ++nt)
        *(h4*)&sm[hb + SWZ(nt * 16 + li, half * 16 + lg * 4, 4)] = pack4(accQ[half][nt]);
#pragma unroll
    for (int it = 0; it < 4; ++it)
      Qf[it] = *(const h8*)&sm[hb + SWZ(it * 16 + li, lg * 8, 4)];
  }

  // ---- V pass (swapped operands): C(row=tok,col=d) -> VT[d][tok] h4 writes ----
  {
    f4 acc[4][2];
#pragma unroll
    for (int ct = 0; ct < 2; ++ct) {
      float bv = qbs[256 + h * 32 + ct * 16 + li];
#pragma unroll
      for (int nt = 0; nt < 4; ++nt) acc[nt][ct] = f4{bv, bv, bv, bv};
    }
#pragma unroll
    for (int ks = 0; ks < 4; ++ks) {
      h8 bW[4];
#pragma unroll
      for (int nt = 0; nt < 4; ++nt)
        bW[nt] = *(const h8*)&sm[RA + SWZ(nt * 16 + li, ks * 32 + lg * 8, 16)];
      h8 wv[2];
#pragma unroll
      for (int ct = 0; ct < 2; ++ct)
        wv[ct] = *(const h8*)(qwh + (size_t)((16 + 2 * h + ct) * 16 + li) * 128 + ks * 32 + lg * 8);
#pragma unroll
      for (int nt = 0; nt < 4; ++nt)
#pragma unroll
        for (int ct = 0; ct < 2; ++ct)
          acc[nt][ct] = __builtin_amdgcn_mfma_f32_16x16x32_f16(bW[nt], wv[ct], acc[nt][ct], 0, 0, 0);
    }
#pragma unroll
    for (int nt = 0; nt < 4; ++nt)
#pragma unroll
      for (int ct = 0; ct < 2; ++ct)
        *(h4*)&sm[hb + SWZ(ct * 16 + li, nt * 16 + lg * 4, 8)] = pack4(acc[nt][ct]);
  }

  // ---- S^T = K . Q^T + bias + mask, softmax in regs ----
  float inv[4];
  h4 P4[4][4];
  {
    f4 s[4][4];
    const _Float16* bT = biasT + h * 4096;
#pragma unroll
    for (int jt = 0; jt < 4; ++jt)
#pragma unroll
      for (int it = 0; it < 4; ++it) {
        h4 bb = *(const h4*)&bT[(jt * 4 + it) * 256 + l * 4];
        s[jt][it] = f4{(float)bb[0], (float)bb[1], (float)bb[2], (float)bb[3]};
      }
    __builtin_amdgcn_s_setprio(1);
#pragma unroll
    for (int jt = 0; jt < 4; ++jt)
#pragma unroll
      for (int it = 0; it < 4; ++it)
        s[jt][it] = __builtin_amdgcn_mfma_f32_16x16x32_f16(Kf[jt], Qf[it], s[jt][it], 0, 0, 0);
    __builtin_amdgcn_s_setprio(0);
#pragma unroll
    for (int jt = 0; jt < 4; ++jt)
#pragma unroll
      for (int it = 0; it < 4; ++it)
#pragma unroll
        for (int r = 0; r < 4; ++r) {
          int j = jt * 16 + lg * 4 + r;
          s[jt][it][r] = (j < NN) ? s[jt][it][r] : -1e30f;
        }
    if (shift && (wh == 15 || ww == 15)) {
      int regi[4], regj[4][4];
#pragma unroll
      for (int it = 0; it < 4; ++it) {
        int i = it * 16 + li;
        regi[it] = rid3(wh * WSZ + i / 7) * 3 + rid3(ww * WSZ + i % 7);
      }
#pragma unroll
      for (int jt = 0; jt < 4; ++jt)
#pragma unroll
        for (int r = 0; r < 4; ++r) {
          int j = jt * 16 + lg * 4 + r;
          regj[jt][r] = rid3(wh * WSZ + j / 7) * 3 + rid3(ww * WSZ + j % 7);
        }
#pragma unroll
      for (int jt = 0; jt < 4; ++jt)
#pragma unroll
        for (int it = 0; it < 4; ++it)
#pragma unroll
          for (int r = 0; r < 4; ++r)
            if (regj[jt][r] != regi[it]) s[jt][it][r] -= 100.f;
    }
#pragma unroll
    for (int it = 0; it < 4; ++it) {
      float mx = -1e30f;
#pragma unroll
      for (int jt = 0; jt < 4; ++jt)
#pragma unroll
        for (int r = 0; r < 4; ++r) mx = fmaxf(mx, s[jt][it][r]);
      mx = fmaxf(mx, __shfl_xor(mx, 16));
      mx = fmaxf(mx, __shfl_xor(mx, 32));
      float sum = 0.f;
#pragma unroll
      for (int jt = 0; jt < 4; ++jt)
#pragma unroll
        for (int r = 0; r < 4; ++r) {
          float e = __expf(s[jt][it][r] - mx);
          s[jt][it][r] = e;
          sum += e;
        }
      sum += __shfl_xor(sum, 16);
      sum += __shfl_xor(sum, 32);
      inv[it] = 1.f / sum;
    }
#pragma unroll
    for (int jt = 0; jt < 4; ++jt)
#pragma unroll
      for (int it = 0; it < 4; ++it)
        P4[jt][it] = pack4(s[jt][it]);
  }

  // ---- PV: load aV (VT dead after), then P halves round-trip region B ----
  f4 o[2][4] = {};
  {
    h8 aV[2][2];
#pragma unroll
    for (int mt = 0; mt < 2; ++mt)
#pragma unroll
      for (int ks = 0; ks < 2; ++ks)
        aV[mt][ks] = *(const h8*)&sm[hb + SWZ(mt * 16 + li, ks * 32 + lg * 8, 8)];
#pragma unroll
    for (int half = 0; half < 2; ++half) {
#pragma unroll
      for (int jt2 = 0; jt2 < 2; ++jt2)
#pragma unroll
        for (int it = 0; it < 4; ++it)
          *(h4*)&sm[hb + SWZ(it * 16 + li, jt2 * 16 + lg * 4, 4)] = P4[half * 2 + jt2][it];
      h8 bP[4];
#pragma unroll
      for (int nt = 0; nt < 4; ++nt)
        bP[nt] = *(const h8*)&sm[hb + SWZ(nt * 16 + li, lg * 8, 4)];
      __builtin_amdgcn_s_setprio(1);
#pragma unroll
      for (int mt = 0; mt < 2; ++mt)
#pragma unroll
        for (int nt = 0; nt < 4; ++nt)
          o[mt][nt] = __builtin_amdgcn_mfma_f32_16x16x32_f16(aV[mt][half], bP[nt], o[mt][nt], 0, 0, 0);
      __builtin_amdgcn_s_setprio(0);
    }
  }

  // ---- prefetch proj weights + bias (latency hides under O-write + B1') ----
  h8 pa[2][4];
  float4 pbb[2];
#pragma unroll
  for (int mi = 0; mi < 2; ++mi) {
    pbb[mi] = *(const float4*)&pb[(w * 2 + mi) * 16 + lg * 4];
#pragma unroll
    for (int ks = 0; ks < 4; ++ks)
      pa[mi][ks] = *(const h8*)(pwh + (size_t)((w * 2 + mi) * 16 + li) * 128 + ks * 32 + lg * 8);
  }

  // ---- O -> own per-head slot [64tok][32d] (P dead; no cross-wave hazard) ----
#pragma unroll
  for (int mt = 0; mt < 2; ++mt)
#pragma unroll
    for (int nt = 0; nt < 4; ++nt) {
      int i = nt * 16 + li;
      float is = inv[nt];
      h4 v = {(_Float16)(o[mt][nt][0] * is), (_Float16)(o[mt][nt][1] * is),
              (_Float16)(o[mt][nt][2] * is), (_Float16)(o[mt][nt][3] * is)};
      *(h4*)&sm[hb + SWZ(i, mt * 16 + lg * 4, 4)] = v;
    }
  __syncthreads();  // B1': all heads' O visible (also orders win reads before Y overlay)

  // ---- proj: y^T = pw . O^T ; k-chunk ks = head slot ks ----
  {
    f4 acc[2][4];
#pragma unroll
    for (int mi = 0; mi < 2; ++mi)
#pragma unroll
      for (int nt = 0; nt < 4; ++nt)
        acc[mi][nt] = f4{pbb[mi].x, pbb[mi].y, pbb[mi].z, pbb[mi].w};
    __builtin_amdgcn_s_setprio(1);
#pragma unroll
    for (int ks = 0; ks < 4; ++ks) {
      h8 bO[4];
#pragma unroll
      for (int nt = 0; nt < 4; ++nt)
        bO[nt] = *(const h8*)&sm[RB + ks * 2048 + SWZ(nt * 16 + li, lg * 8, 4)];
#pragma unroll
      for (int mi = 0; mi < 2; ++mi)
#pragma unroll
        for (int nt = 0; nt < 4; ++nt)
          acc[mi][nt] = __builtin_amdgcn_mfma_f32_16x16x32_f16(pa[mi][ks], bO[nt], acc[mi][nt], 0, 0, 0);
    }
    __builtin_amdgcn_s_setprio(0);
    if (!writeN) {
      // layer 0: bounce y through region A (win dead post-B1'), coalesced h8 stores
#pragma unroll
      for (int mi = 0; mi < 2; ++mi) {
        int dbase = (w * 2 + mi) * 16 + lg * 4;
#pragma unroll
        for (int nt = 0; nt < 4; ++nt) {
          int i = nt * 16 + li;
          h4 v = {(_Float16)acc[mi][nt][0], (_Float16)acc[mi][nt][1],
                  (_Float16)acc[mi][nt][2], (_Float16)acc[mi][nt][3]};
          *(h4*)&sm[RA + SWZ(i, dbase, 16)] = v;
        }
      }
      __syncthreads();  // B3
      for (int cidx = tid; cidx < NN * 16; cidx += 256) {
        int tok = cidx >> 4, c = cidx & 15;
        h8 v = *(const h8*)&sm[RA + SWZ(tok, c * 8, 16)];
        int gh = wh * WSZ + tok / 7;
        int gw = ww * WSZ + tok % 7;
        *(h8*)&toutB[((size_t)(b * HH + gh) * HH + gw) * CC + c * 8] = v;
      }
    } else {
      // layer 1: direct f32 stores with fused NCHW transpose + roll
#pragma unroll
      for (int mi = 0; mi < 2; ++mi) {
        int dbase = (w * 2 + mi) * 16 + lg * 4;
#pragma unroll
        for (int nt = 0; nt < 4; ++nt) {
          int i = nt * 16 + li;
          if (i < NN) {
            int gh = wh * WSZ + i / 7 + shift; if (gh >= HH) gh -= HH;
            int gw = ww * WSZ + i % 7 + shift; if (gw >= HH) gw -= HH;
            size_t bse = ((size_t)(b * CC + dbase) * HH + gh) * HH + gw;
            outN[bse] = acc[mi][nt][0];
            outN[bse + (size_t)HH * HH] = acc[mi][nt][1];
            outN[bse + (size_t)2 * HH * HH] = acc[mi][nt][2];
            outN[bse + (size_t)3 * HH * HH] = acc[mi][nt][3];
          }
        }
      }
    }
  }
}

extern "C" void kernel_launch(void* const* d_in, const int* in_sizes, int n_in,
                              void* d_out, int out_size, void* d_ws, size_t ws_size,
                              hipStream_t stream) {
  const float* x = (const float*)d_in[0];
  const float* cw = (const float*)d_in[1];
  const float* cb = (const float*)d_in[2];
  const float* qkvw = (const float*)d_in[3];  // (2,384,128)
  const float* qkvb = (const float*)d_in[4];  // (2,384)
  const float* projw = (const float*)d_in[5]; // (2,128,128)
  const float* projb = (const float*)d_in[6]; // (2,128)
  const float* rpb = (const float*)d_in[7];   // (2,169,4)
  float* out = (float*)d_out;

  char* ws = (char*)d_ws;
  _Float16* t0 = (_Float16*)ws;                       // 16*112*112*128 fp16
  size_t off = (size_t)BB * HH * HH * CC * 2;
  _Float16* qwh = (_Float16*)(ws + off);  off += 2 * 384 * 128 * 2;
  _Float16* pwh = (_Float16*)(ws + off);  off += 2 * 128 * 128 * 2;
  float* qbs = (float*)(ws + off);        off += 2 * 384 * 4;
  _Float16* biasT = (_Float16*)(ws + off);  // 2*16384*2

  prep<<<224, 256, 0, stream>>>(qkvw, qkvb, projw, rpb, qwh, qbs, pwh, biasT);
  conv_embed<<<BB * HH, 256, 0, stream>>>(x, cw, cb, t0);

  // layer 0: no shift, in-place on t0 (windows partition tokens)
  swin_layer<<<4096, 256, 0, stream>>>(t0, t0, nullptr,
      qwh, qbs, pwh, projb, biasT, 0, 0);
  // layer 1: shift=3, fused NCHW transpose into d_out
  swin_layer<<<4096, 256, 0, stream>>>(t0, nullptr, out,
      qwh + 384 * 128, qbs + 384, pwh + 128 * 128, projb + 128,
      biasT + 16384, SH, 1);
}